// Round 4
// baseline (317.068 us; speedup 1.0000x reference)
//
#include <hip/hip_runtime.h>
#include <hip/hip_bf16.h>
#include <math.h>

#define BB    8
#define NN    512
#define DD    768
#define DEPD  64
#define ITILE 8

__device__ __forceinline__ unsigned short to_bf16(float x) {
    __hip_bfloat16 h = __float2bfloat16(x);       // RNE
    return __builtin_bit_cast(unsigned short, h);
}
__device__ __forceinline__ float bf_lo(unsigned int u) { return __uint_as_float(u << 16); }
__device__ __forceinline__ float bf_hi(unsigned int u) { return __uint_as_float(u & 0xFFFF0000u); }

// ---------------- kernel 1: s_nbr[b,j] = f·w_nbr, s_asp[b,j] = f·w_asp ----
// (proven rounds 1/3, unchanged)
__global__ __launch_bounds__(256) void k_proj(const float* __restrict__ feat,
                                              const float* __restrict__ watt,
                                              float* __restrict__ snbr,
                                              float* __restrict__ sasp)
{
    int flat = blockIdx.x * 4 + (threadIdx.x >> 6);   // b*N + j
    int lane = threadIdx.x & 63;
    const float* frow = feat + (size_t)flat * DD + lane * 4;
    const float* wn   = watt + lane * 4;              // w_nbr = w[:768]
    const float* wa   = watt + DD + DEPD + lane * 4;  // w_asp = w[832:1600]
    float accn = 0.f, acca = 0.f;
#pragma unroll
    for (int k = 0; k < 3; ++k) {
        float4 f = *(const float4*)(frow + k * 256);
        float4 n = *(const float4*)(wn + k * 256);
        float4 a = *(const float4*)(wa + k * 256);
        accn += f.x*n.x + f.y*n.y + f.z*n.z + f.w*n.w;
        acca += f.x*a.x + f.y*a.y + f.z*a.z + f.w*a.w;
    }
#pragma unroll
    for (int off = 1; off < 64; off <<= 1) {
        accn += __shfl_xor(accn, off);
        acca += __shfl_xor(acca, off);
    }
    if (lane == 0) { snbr[flat] = accn; sasp[flat] = acca; }
}

// ---------------- fused: sdep + softmax + aggregation + select ------------
// block = (b, 8-row i-tile); 512 blocks (2/CU), 256 threads.
__global__ __launch_bounds__(256) void k_fused(const float* __restrict__ feat,
                                               const int*   __restrict__ aspect,
                                               const float* __restrict__ adj,
                                               const float* __restrict__ watt,
                                               const float* __restrict__ snbr,
                                               const float* __restrict__ sasp,
                                               float* __restrict__ out)
{
    int blk = blockIdx.x;                 // b*64 + tile
    int b   = blk >> 6;
    int i0  = (blk & 63) * ITILE;
    int tid = threadIdx.x;
    int g = tid >> 4, l = tid & 15;

    __shared__ float s_nbr[NN];                               // 2 KB
    __shared__ float sdep[ITILE][NN];                         // 16 KB, -INF = masked
    __shared__ __align__(16) unsigned short wl[NN][ITILE];    // 8 KB, bf16 [j][i]
    __shared__ int sflag[ITILE];

    // stage snbr[b,:] (needed in phase 2; phase-1 barrier covers it)
    s_nbr[tid]       = snbr[(b << 9) + tid];
    s_nbr[tid + 256] = snbr[(b << 9) + tid + 256];

    // ---- phase 1: stream adj tile, compute sdep ----
    float4 wd = *(const float4*)(watt + DD + l * 4);          // w_dep
    const float* abase = adj + ((size_t)(b * NN + i0)) * NN * DEPD;
#pragma unroll 4
    for (int it = 0; it < 256; ++it) {
        int e = it * 16 + g;              // (i,j): i=e>>9, j=e&511
        float4 a = *(const float4*)(abase + (size_t)e * DEPD + l * 4);
        float p  = a.x*wd.x + a.y*wd.y + a.z*wd.z + a.w*wd.w;
        int   nz = (a.x != 0.f) | (a.y != 0.f) | (a.z != 0.f) | (a.w != 0.f);
#pragma unroll
        for (int off = 1; off < 16; off <<= 1) {
            p  += __shfl_xor(p, off);
            nz |= __shfl_xor(nz, off);
        }
        if (l == 0) sdep[e >> 9][e & 511] = nz ? p : -INFINITY;
    }
    __syncthreads();

    // ---- phase 2: per-wave exact softmax, 2 rows per wave ----
    int wave = tid >> 6, lane = tid & 63;
#pragma unroll
    for (int rr = 0; rr < 2; ++rr) {
        int r   = wave * 2 + rr;
        int row = b * NN + i0 + r;
        float sa = sasp[row];
        float sc[8];
        float mx = -INFINITY;
#pragma unroll
        for (int m = 0; m < 8; ++m) {
            int j = lane + 64 * m;
            float s = sdep[r][j] + s_nbr[j] + sa;   // -INF stays -INF
            sc[m] = s;
            mx = fmaxf(mx, s);
        }
#pragma unroll
        for (int off = 1; off < 64; off <<= 1) mx = fmaxf(mx, __shfl_xor(mx, off));
        float sum = 0.f, ev[8];
#pragma unroll
        for (int m = 0; m < 8; ++m) {
            ev[m] = sc[m] > -1e37f ? __expf(sc[m] - mx) : 0.f;
            sum += ev[m];
        }
#pragma unroll
        for (int off = 1; off < 64; off <<= 1) sum += __shfl_xor(sum, off);
        float inv = sum > 0.f ? 1.f / sum : 0.f;
#pragma unroll
        for (int m = 0; m < 8; ++m) wl[lane + 64 * m][r] = to_bf16(ev[m] * inv);
        if (lane == 0) sflag[r] = (aspect[row] != 0) && (mx > -1e37f);
    }
    __syncthreads();

    // ---- phase 3: agg. thread owns (d, d+256, d+512) x 8 rows ----
    float acc[ITILE][3];
#pragma unroll
    for (int r = 0; r < ITILE; ++r) { acc[r][0] = 0.f; acc[r][1] = 0.f; acc[r][2] = 0.f; }

    const float* fb = feat + (size_t)b * NN * DD;
    int d0 = tid, d1 = tid + 256, d2 = tid + 512;

#pragma unroll 2
    for (int j = 0; j < NN; ++j) {
        const float* fr = fb + (size_t)j * DD;
        float f0 = fr[d0], f1 = fr[d1], f2 = fr[d2];
        uint4 wq = *(const uint4*)&wl[j][0];      // 16 B uniform broadcast
        float w0 = bf_lo(wq.x), w1 = bf_hi(wq.x);
        float w2 = bf_lo(wq.y), w3 = bf_hi(wq.y);
        float w4 = bf_lo(wq.z), w5 = bf_hi(wq.z);
        float w6 = bf_lo(wq.w), w7 = bf_hi(wq.w);
        acc[0][0] = fmaf(w0, f0, acc[0][0]); acc[0][1] = fmaf(w0, f1, acc[0][1]); acc[0][2] = fmaf(w0, f2, acc[0][2]);
        acc[1][0] = fmaf(w1, f0, acc[1][0]); acc[1][1] = fmaf(w1, f1, acc[1][1]); acc[1][2] = fmaf(w1, f2, acc[1][2]);
        acc[2][0] = fmaf(w2, f0, acc[2][0]); acc[2][1] = fmaf(w2, f1, acc[2][1]); acc[2][2] = fmaf(w2, f2, acc[2][2]);
        acc[3][0] = fmaf(w3, f0, acc[3][0]); acc[3][1] = fmaf(w3, f1, acc[3][1]); acc[3][2] = fmaf(w3, f2, acc[3][2]);
        acc[4][0] = fmaf(w4, f0, acc[4][0]); acc[4][1] = fmaf(w4, f1, acc[4][1]); acc[4][2] = fmaf(w4, f2, acc[4][2]);
        acc[5][0] = fmaf(w5, f0, acc[5][0]); acc[5][1] = fmaf(w5, f1, acc[5][1]); acc[5][2] = fmaf(w5, f2, acc[5][2]);
        acc[6][0] = fmaf(w6, f0, acc[6][0]); acc[6][1] = fmaf(w6, f1, acc[6][1]); acc[6][2] = fmaf(w6, f2, acc[6][2]);
        acc[7][0] = fmaf(w7, f0, acc[7][0]); acc[7][1] = fmaf(w7, f1, acc[7][1]); acc[7][2] = fmaf(w7, f2, acc[7][2]);
    }

    // ---- epilogue: out = upd ? acc : feat ----
#pragma unroll
    for (int r = 0; r < ITILE; ++r) {
        size_t row = (size_t)(b * NN + i0 + r) * DD;
        float o0 = acc[r][0], o1 = acc[r][1], o2 = acc[r][2];
        if (!sflag[r]) {                          // block-uniform branch
            o0 = feat[row + d0]; o1 = feat[row + d1]; o2 = feat[row + d2];
        }
        out[row + d0] = o0; out[row + d1] = o1; out[row + d2] = o2;
    }
}

extern "C" void kernel_launch(void* const* d_in, const int* in_sizes, int n_in,
                              void* d_out, int out_size, void* d_ws, size_t ws_size,
                              hipStream_t stream)
{
    (void)in_sizes; (void)n_in; (void)out_size; (void)ws_size;
    const float* feat = (const float*)d_in[0];
    const int*   asp  = (const int*)d_in[1];
    const float* adj  = (const float*)d_in[2];
    const float* watt = (const float*)d_in[3];
    float* out = (float*)d_out;

    // workspace: snbr[4096] | sasp[4096]
    float* snbr = (float*)d_ws;
    float* sasp = snbr + BB * NN;

    k_proj<<<BB * NN / 4, 256, 0, stream>>>(feat, watt, snbr, sasp);
    k_fused<<<BB * (NN / ITILE), 256, 0, stream>>>(feat, asp, adj, watt, snbr, sasp, out);
}

// Round 5
// 239.212 us; speedup vs baseline: 1.3255x; 1.3255x over previous
//
#include <hip/hip_runtime.h>
#include <hip/hip_bf16.h>
#include <math.h>

#define BB    8
#define NN    512
#define DD    768
#define DEPD  64
#define ITILE 8

__device__ __forceinline__ unsigned short to_bf16(float x) {
    __hip_bfloat16 h = __float2bfloat16(x);       // RNE
    return __builtin_bit_cast(unsigned short, h);
}
__device__ __forceinline__ float bf_lo(unsigned int u) { return __uint_as_float(u << 16); }
__device__ __forceinline__ float bf_hi(unsigned int u) { return __uint_as_float(u & 0xFFFF0000u); }

// ---------------- kernel 1: s_nbr[b,j] = f·w_nbr, s_asp[b,j] = f·w_asp ----
__global__ __launch_bounds__(256) void k_proj(const float* __restrict__ feat,
                                              const float* __restrict__ watt,
                                              float* __restrict__ snbr,
                                              float* __restrict__ sasp)
{
    int flat = blockIdx.x * 4 + (threadIdx.x >> 6);   // b*N + j
    int lane = threadIdx.x & 63;
    const float* frow = feat + (size_t)flat * DD + lane * 4;
    const float* wn   = watt + lane * 4;              // w_nbr = w[:768]
    const float* wa   = watt + DD + DEPD + lane * 4;  // w_asp = w[832:1600]
    float accn = 0.f, acca = 0.f;
#pragma unroll
    for (int k = 0; k < 3; ++k) {
        float4 f = *(const float4*)(frow + k * 256);
        float4 n = *(const float4*)(wn + k * 256);
        float4 a = *(const float4*)(wa + k * 256);
        accn += f.x*n.x + f.y*n.y + f.z*n.z + f.w*n.w;
        acca += f.x*a.x + f.y*a.y + f.z*a.z + f.w*a.w;
    }
#pragma unroll
    for (int off = 1; off < 64; off <<= 1) {
        accn += __shfl_xor(accn, off);
        acca += __shfl_xor(acca, off);
    }
    if (lane == 0) { snbr[flat] = accn; sasp[flat] = acca; }
}

// ---------------- kernel 2: sdep + masked softmax -> bf16 weights ---------
// round-1 proven body (4096 blocks, one (b,i) row each); stores changed to
// bf16 ROW-major wtsB[b][i][j] (coalesced).
__global__ __launch_bounds__(256) void k_score(const float* __restrict__ adj,
                                               const float* __restrict__ snbr,
                                               const float* __restrict__ sasp,
                                               const int* __restrict__ aspect,
                                               const float* __restrict__ watt,
                                               unsigned short* __restrict__ wtsB,
                                               int* __restrict__ upd)
{
    int bi  = blockIdx.x;          // b*N + i
    int b   = bi >> 9;
    int tid = threadIdx.x;
    int g = tid >> 4, l = tid & 15;

    __shared__ float sdep[NN];
    __shared__ int   smsk[NN];
    __shared__ float sred[4];

    float4 wd = *(const float4*)(watt + DD + l * 4);   // w_dep = w[768:832]

    const float* arow = adj + (size_t)bi * NN * DEPD;
#pragma unroll 4
    for (int it = 0; it < NN / 16; ++it) {
        int j = it * 16 + g;
        float4 a = *(const float4*)(arow + (size_t)j * DEPD + l * 4);
        float p  = a.x*wd.x + a.y*wd.y + a.z*wd.z + a.w*wd.w;
        int   nz = (a.x != 0.f) | (a.y != 0.f) | (a.z != 0.f) | (a.w != 0.f);
#pragma unroll
        for (int off = 1; off < 16; off <<= 1) {
            p  += __shfl_xor(p, off);
            nz |= __shfl_xor(nz, off);
        }
        if (l == 0) { sdep[j] = p; smsk[j] = nz; }
    }
    __syncthreads();

    float sa = sasp[bi];
    int j0 = tid, j1 = tid + 256;
    float sc0 = sdep[j0] + snbr[(b << 9) + j0] + sa;
    float sc1 = sdep[j1] + snbr[(b << 9) + j1] + sa;
    int m0 = smsk[j0], m1 = smsk[j1];

    float v = fmaxf(m0 ? sc0 : -INFINITY, m1 ? sc1 : -INFINITY);
#pragma unroll
    for (int off = 1; off < 64; off <<= 1) v = fmaxf(v, __shfl_xor(v, off));
    if ((tid & 63) == 0) sred[tid >> 6] = v;
    __syncthreads();
    float mx = fmaxf(fmaxf(sred[0], sred[1]), fmaxf(sred[2], sred[3]));
    __syncthreads();

    float e0 = m0 ? __expf(sc0 - mx) : 0.f;
    float e1 = m1 ? __expf(sc1 - mx) : 0.f;
    v = e0 + e1;
#pragma unroll
    for (int off = 1; off < 64; off <<= 1) v += __shfl_xor(v, off);
    if ((tid & 63) == 0) sred[tid >> 6] = v;
    __syncthreads();
    float sm = sred[0] + sred[1] + sred[2] + sred[3];

    float inv = sm > 0.f ? 1.f / sm : 0.f;
    size_t wb = (size_t)bi * NN;
    wtsB[wb + j0] = to_bf16(e0 * inv);     // coalesced 2B stores
    wtsB[wb + j1] = to_bf16(e1 * inv);
    if (tid == 0) upd[bi] = (aspect[bi] != 0) && (mx > -1e37f);
}

// ---------------- kernel 3: out = upd ? weights@features : features -------
// 512 blocks = (b, 8-row i-tile); thread owns d, d+256, d+512.
// Weights bf16 in LDS [j][8i]: ONE uniform ds_read_b128 per wave per j
// (LDS pipe 8 cyc vs ~64 VALU cyc -> VALU-bound at the 20.5 us floor).
__global__ __launch_bounds__(256) void k_agg(const float* __restrict__ feat,
                                             const unsigned short* __restrict__ wtsB,
                                             const int* __restrict__ upd,
                                             float* __restrict__ out)
{
    int blk = blockIdx.x;                 // b*64 + tile
    int b   = blk >> 6;
    int i0  = (blk & 63) * ITILE;
    int tid = threadIdx.x;

    __shared__ __align__(16) unsigned short wl[NN][ITILE];   // 8 KB, [j][i]

    // stage: global [i][j] coalesced -> LDS [j][i]
    const unsigned short* wsrc = wtsB + (size_t)(b * NN + i0) * NN;
#pragma unroll
    for (int k = 0; k < ITILE * NN / 256; ++k) {             // 16 iters
        int e = k * 256 + tid;
        int i = e >> 9;          // uniform per iteration
        int j = e & 511;         // consecutive lanes -> coalesced
        wl[j][i] = wsrc[(size_t)i * NN + j];
    }
    __syncthreads();

    float acc[ITILE][3];
#pragma unroll
    for (int r = 0; r < ITILE; ++r) { acc[r][0] = 0.f; acc[r][1] = 0.f; acc[r][2] = 0.f; }

    const float* fb = feat + (size_t)b * NN * DD;
    int d0 = tid, d1 = tid + 256, d2 = tid + 512;

#pragma unroll 4
    for (int j = 0; j < NN; ++j) {
        const float* fr = fb + (size_t)j * DD;
        float f0 = fr[d0], f1 = fr[d1], f2 = fr[d2];
        uint4 wq = *(const uint4*)&wl[j][0];      // 16 B uniform broadcast
        float w0 = bf_lo(wq.x), w1 = bf_hi(wq.x);
        float w2 = bf_lo(wq.y), w3 = bf_hi(wq.y);
        float w4 = bf_lo(wq.z), w5 = bf_hi(wq.z);
        float w6 = bf_lo(wq.w), w7 = bf_hi(wq.w);
        acc[0][0] = fmaf(w0, f0, acc[0][0]); acc[0][1] = fmaf(w0, f1, acc[0][1]); acc[0][2] = fmaf(w0, f2, acc[0][2]);
        acc[1][0] = fmaf(w1, f0, acc[1][0]); acc[1][1] = fmaf(w1, f1, acc[1][1]); acc[1][2] = fmaf(w1, f2, acc[1][2]);
        acc[2][0] = fmaf(w2, f0, acc[2][0]); acc[2][1] = fmaf(w2, f1, acc[2][1]); acc[2][2] = fmaf(w2, f2, acc[2][2]);
        acc[3][0] = fmaf(w3, f0, acc[3][0]); acc[3][1] = fmaf(w3, f1, acc[3][1]); acc[3][2] = fmaf(w3, f2, acc[3][2]);
        acc[4][0] = fmaf(w4, f0, acc[4][0]); acc[4][1] = fmaf(w4, f1, acc[4][1]); acc[4][2] = fmaf(w4, f2, acc[4][2]);
        acc[5][0] = fmaf(w5, f0, acc[5][0]); acc[5][1] = fmaf(w5, f1, acc[5][1]); acc[5][2] = fmaf(w5, f2, acc[5][2]);
        acc[6][0] = fmaf(w6, f0, acc[6][0]); acc[6][1] = fmaf(w6, f1, acc[6][1]); acc[6][2] = fmaf(w6, f2, acc[6][2]);
        acc[7][0] = fmaf(w7, f0, acc[7][0]); acc[7][1] = fmaf(w7, f1, acc[7][1]); acc[7][2] = fmaf(w7, f2, acc[7][2]);
    }

#pragma unroll
    for (int r = 0; r < ITILE; ++r) {
        int rowi = b * NN + i0 + r;
        size_t row = (size_t)rowi * DD;
        float o0 = acc[r][0], o1 = acc[r][1], o2 = acc[r][2];
        if (!upd[rowi]) {                         // block-uniform branch
            o0 = feat[row + d0]; o1 = feat[row + d1]; o2 = feat[row + d2];
        }
        out[row + d0] = o0; out[row + d1] = o1; out[row + d2] = o2;
    }
}

extern "C" void kernel_launch(void* const* d_in, const int* in_sizes, int n_in,
                              void* d_out, int out_size, void* d_ws, size_t ws_size,
                              hipStream_t stream)
{
    (void)in_sizes; (void)n_in; (void)out_size; (void)ws_size;
    const float* feat = (const float*)d_in[0];
    const int*   asp  = (const int*)d_in[1];
    const float* adj  = (const float*)d_in[2];
    const float* watt = (const float*)d_in[3];
    float* out = (float*)d_out;

    // workspace: wtsB bf16 [8][512][512] (4MB) | snbr | sasp | upd
    unsigned short* wtsB = (unsigned short*)d_ws;
    float* snbr = (float*)(wtsB + (size_t)BB * NN * NN);
    float* sasp = snbr + BB * NN;
    int*   upd  = (int*)(sasp + BB * NN);

    k_proj<<<BB * NN / 4, 256, 0, stream>>>(feat, watt, snbr, sasp);
    k_score<<<BB * NN, 256, 0, stream>>>(adj, snbr, sasp, asp, watt, wtsB, upd);
    k_agg<<<BB * (NN / ITILE), 256, 0, stream>>>(feat, wtsB, upd, out);
}

// Round 6
// 197.308 us; speedup vs baseline: 1.6070x; 1.2124x over previous
//
#include <hip/hip_runtime.h>
#include <hip/hip_bf16.h>
#include <math.h>

#define BB    8
#define NN    512
#define DD    768
#define DEPD  64
#define ITILE 16

__device__ __forceinline__ unsigned short to_bf16(float x) {
    __hip_bfloat16 h = __float2bfloat16(x);       // RNE
    return __builtin_bit_cast(unsigned short, h);
}
__device__ __forceinline__ float bf_lo(unsigned int u) { return __uint_as_float(u << 16); }
__device__ __forceinline__ float bf_hi(unsigned int u) { return __uint_as_float(u & 0xFFFF0000u); }

// ---------------- kernel 1: s_nbr[b,j] = f·w_nbr, s_asp[b,j] = f·w_asp ----
__global__ __launch_bounds__(256) void k_proj(const float* __restrict__ feat,
                                              const float* __restrict__ watt,
                                              float* __restrict__ snbr,
                                              float* __restrict__ sasp)
{
    int flat = blockIdx.x * 4 + (threadIdx.x >> 6);   // b*N + j
    int lane = threadIdx.x & 63;
    const float* frow = feat + (size_t)flat * DD + lane * 4;
    const float* wn   = watt + lane * 4;              // w_nbr = w[:768]
    const float* wa   = watt + DD + DEPD + lane * 4;  // w_asp = w[832:1600]
    float accn = 0.f, acca = 0.f;
#pragma unroll
    for (int k = 0; k < 3; ++k) {
        float4 f = *(const float4*)(frow + k * 256);
        float4 n = *(const float4*)(wn + k * 256);
        float4 a = *(const float4*)(wa + k * 256);
        accn += f.x*n.x + f.y*n.y + f.z*n.z + f.w*n.w;
        acca += f.x*a.x + f.y*a.y + f.z*a.z + f.w*a.w;
    }
#pragma unroll
    for (int off = 1; off < 64; off <<= 1) {
        accn += __shfl_xor(accn, off);
        acca += __shfl_xor(acca, off);
    }
    if (lane == 0) { snbr[flat] = accn; sasp[flat] = acca; }
}

// ---------------- kernel 2: sdep + masked softmax -> bf16 weights ---------
// R5 proven body, two local deltas: nz-reduce via one __ballot (shuffle
// chain halved), masked sentinel kept in sdep (smsk array dropped).
__global__ __launch_bounds__(256) void k_score(const float* __restrict__ adj,
                                               const float* __restrict__ snbr,
                                               const float* __restrict__ sasp,
                                               const int* __restrict__ aspect,
                                               const float* __restrict__ watt,
                                               unsigned short* __restrict__ wtsB,
                                               int* __restrict__ upd)
{
    int bi  = blockIdx.x;          // b*N + i
    int b   = bi >> 9;
    int tid = threadIdx.x;
    int g = tid >> 4, l = tid & 15;

    __shared__ float sdep[NN];     // -INF = masked
    __shared__ float sred[4];

    float4 wd = *(const float4*)(watt + DD + l * 4);   // w_dep = w[768:832]

    const float* arow = adj + (size_t)bi * NN * DEPD;
#pragma unroll 4
    for (int it = 0; it < NN / 16; ++it) {
        int j = it * 16 + g;
        float4 a = *(const float4*)(arow + (size_t)j * DEPD + l * 4);
        float p  = a.x*wd.x + a.y*wd.y + a.z*wd.z + a.w*wd.w;
        int   nz = (a.x != 0.f) | (a.y != 0.f) | (a.z != 0.f) | (a.w != 0.f);
        unsigned long long bal = __ballot(nz);
        unsigned int gnz = (unsigned int)((bal >> ((g & 3) * 16)) & 0xFFFFull);
        p += __shfl_xor(p, 1);
        p += __shfl_xor(p, 2);
        p += __shfl_xor(p, 4);
        p += __shfl_xor(p, 8);
        if (l == 0) sdep[j] = gnz ? p : -INFINITY;
    }
    __syncthreads();

    float sa = sasp[bi];
    int j0 = tid, j1 = tid + 256;
    float d0 = sdep[j0], d1 = sdep[j1];
    float sc0 = d0 + snbr[(b << 9) + j0] + sa;   // -INF stays -INF
    float sc1 = d1 + snbr[(b << 9) + j1] + sa;

    float v = fmaxf(sc0, sc1);
#pragma unroll
    for (int off = 1; off < 64; off <<= 1) v = fmaxf(v, __shfl_xor(v, off));
    if ((tid & 63) == 0) sred[tid >> 6] = v;
    __syncthreads();
    float mx = fmaxf(fmaxf(sred[0], sred[1]), fmaxf(sred[2], sred[3]));
    __syncthreads();

    float e0 = d0 > -1e37f ? __expf(sc0 - mx) : 0.f;
    float e1 = d1 > -1e37f ? __expf(sc1 - mx) : 0.f;
    v = e0 + e1;
#pragma unroll
    for (int off = 1; off < 64; off <<= 1) v += __shfl_xor(v, off);
    if ((tid & 63) == 0) sred[tid >> 6] = v;
    __syncthreads();
    float sm = sred[0] + sred[1] + sred[2] + sred[3];

    float inv = sm > 0.f ? 1.f / sm : 0.f;
    size_t wb = (size_t)bi * NN;
    wtsB[wb + j0] = to_bf16(e0 * inv);     // coalesced 2B stores
    wtsB[wb + j1] = to_bf16(e1 * inv);
    if (tid == 0) upd[bi] = (aspect[bi] != 0) && (mx > -1e37f);
}

// ---------------- kernel 3: out = upd ? weights@features : features -------
// 768 blocks = (b, 16-row i-tile, 256-col d-chunk): 3 blocks/CU, 12 waves/CU.
// Per wave per j: 2 uniform ds_read_b128 (broadcast) + 16 unpack + 16 FMA
// + 1 coalesced feat load -> VALU-bound ~45us with LDS-pipe headroom.
__global__ __launch_bounds__(256, 3) void k_agg(const float* __restrict__ feat,
                                                const unsigned short* __restrict__ wtsB,
                                                const int* __restrict__ upd,
                                                float* __restrict__ out)
{
    int blk = blockIdx.x;                 // b*96 + t*3 + c
    int b   = blk / 96;
    int rem = blk % 96;
    int t   = rem / 3, c = rem % 3;
    int i0  = t * ITILE;
    int tid = threadIdx.x;
    int d   = c * 256 + tid;

    __shared__ __align__(16) unsigned short wl[NN][ITILE];   // 16 KB, [j][i]

    // stage: global bf16 [i][j] (coalesced 2B) -> LDS [j][i]; one-time cost
    const unsigned short* wsrc = wtsB + (size_t)(b * NN + i0) * NN;
#pragma unroll
    for (int k = 0; k < ITILE * NN / 256; ++k) {             // 32 iters
        int e = k * 256 + tid;
        int i = e >> 9;          // uniform per iteration
        int j = e & 511;         // consecutive lanes -> coalesced
        wl[j][i] = wsrc[(size_t)i * NN + j];
    }
    __syncthreads();

    float acc[ITILE];
#pragma unroll
    for (int r = 0; r < ITILE; ++r) acc[r] = 0.f;

    const float* fb = feat + (size_t)b * NN * DD + d;

#pragma unroll 4
    for (int j = 0; j < NN; ++j) {
        float f = fb[(size_t)j * DD];
        uint4 wq0 = *(const uint4*)&wl[j][0];     // 16 B uniform broadcast
        uint4 wq1 = *(const uint4*)&wl[j][8];
        acc[0]  = fmaf(bf_lo(wq0.x), f, acc[0]);
        acc[1]  = fmaf(bf_hi(wq0.x), f, acc[1]);
        acc[2]  = fmaf(bf_lo(wq0.y), f, acc[2]);
        acc[3]  = fmaf(bf_hi(wq0.y), f, acc[3]);
        acc[4]  = fmaf(bf_lo(wq0.z), f, acc[4]);
        acc[5]  = fmaf(bf_hi(wq0.z), f, acc[5]);
        acc[6]  = fmaf(bf_lo(wq0.w), f, acc[6]);
        acc[7]  = fmaf(bf_hi(wq0.w), f, acc[7]);
        acc[8]  = fmaf(bf_lo(wq1.x), f, acc[8]);
        acc[9]  = fmaf(bf_hi(wq1.x), f, acc[9]);
        acc[10] = fmaf(bf_lo(wq1.y), f, acc[10]);
        acc[11] = fmaf(bf_hi(wq1.y), f, acc[11]);
        acc[12] = fmaf(bf_lo(wq1.z), f, acc[12]);
        acc[13] = fmaf(bf_hi(wq1.z), f, acc[13]);
        acc[14] = fmaf(bf_lo(wq1.w), f, acc[14]);
        acc[15] = fmaf(bf_hi(wq1.w), f, acc[15]);
    }

#pragma unroll
    for (int r = 0; r < ITILE; ++r) {
        int rowi = b * NN + i0 + r;
        size_t row = (size_t)rowi * DD;
        float o = upd[rowi] ? acc[r] : feat[row + d];
        out[row + d] = o;
    }
}

extern "C" void kernel_launch(void* const* d_in, const int* in_sizes, int n_in,
                              void* d_out, int out_size, void* d_ws, size_t ws_size,
                              hipStream_t stream)
{
    (void)in_sizes; (void)n_in; (void)out_size; (void)ws_size;
    const float* feat = (const float*)d_in[0];
    const int*   asp  = (const int*)d_in[1];
    const float* adj  = (const float*)d_in[2];
    const float* watt = (const float*)d_in[3];
    float* out = (float*)d_out;

    // workspace: wtsB bf16 [8][512][512] (4MB) | snbr | sasp | upd
    unsigned short* wtsB = (unsigned short*)d_ws;
    float* snbr = (float*)(wtsB + (size_t)BB * NN * NN);
    float* sasp = snbr + BB * NN;
    int*   upd  = (int*)(sasp + BB * NN);

    k_proj<<<BB * NN / 4, 256, 0, stream>>>(feat, watt, snbr, sasp);
    k_score<<<BB * NN, 256, 0, stream>>>(adj, snbr, sasp, asp, watt, wtsB, upd);
    k_agg<<<BB * (NN / ITILE) * 3, 256, 0, stream>>>(feat, wtsB, upd, out);
}

// Round 7
// 160.978 us; speedup vs baseline: 1.9696x; 1.2257x over previous
//
#include <hip/hip_runtime.h>
#include <hip/hip_bf16.h>
#include <math.h>

#define BB    8
#define NN    512
#define DD    768
#define DEPD  64

typedef __attribute__((ext_vector_type(4))) float f32x4;
typedef __attribute__((ext_vector_type(8))) short bf16x8;

__device__ __forceinline__ unsigned short to_bf16(float x) {
    __hip_bfloat16 h = __float2bfloat16(x);       // RNE
    return __builtin_bit_cast(unsigned short, h);
}

// ---------------- kernel 1: s_nbr[b,j] = f·w_nbr, s_asp[b,j] = f·w_asp ----
__global__ __launch_bounds__(256) void k_proj(const float* __restrict__ feat,
                                              const float* __restrict__ watt,
                                              float* __restrict__ snbr,
                                              float* __restrict__ sasp)
{
    int flat = blockIdx.x * 4 + (threadIdx.x >> 6);   // b*N + j
    int lane = threadIdx.x & 63;
    const float* frow = feat + (size_t)flat * DD + lane * 4;
    const float* wn   = watt + lane * 4;              // w_nbr = w[:768]
    const float* wa   = watt + DD + DEPD + lane * 4;  // w_asp = w[832:1600]
    float accn = 0.f, acca = 0.f;
#pragma unroll
    for (int k = 0; k < 3; ++k) {
        float4 f = *(const float4*)(frow + k * 256);
        float4 n = *(const float4*)(wn + k * 256);
        float4 a = *(const float4*)(wa + k * 256);
        accn += f.x*n.x + f.y*n.y + f.z*n.z + f.w*n.w;
        acca += f.x*a.x + f.y*a.y + f.z*a.z + f.w*a.w;
    }
#pragma unroll
    for (int off = 1; off < 64; off <<= 1) {
        accn += __shfl_xor(accn, off);
        acca += __shfl_xor(acca, off);
    }
    if (lane == 0) { snbr[flat] = accn; sasp[flat] = acca; }
}

// ---------------- kernel 1b: featT[b][d][j] = bf16(feat[b][j][d]) ---------
// 64x64 tile transpose through padded LDS; coalesced both sides.
__global__ __launch_bounds__(256) void k_cast(const float* __restrict__ feat,
                                              unsigned short* __restrict__ featT)
{
    int b  = blockIdx.z;
    int j0 = blockIdx.y * 64;
    int d0 = blockIdx.x * 64;
    int t  = threadIdx.x;

    __shared__ unsigned short lt[64][65];

    int dd = t & 63, j4 = t >> 6;
#pragma unroll
    for (int it = 0; it < 16; ++it) {
        int jj = j4 * 16 + it;
        float v = feat[((size_t)(b * NN) + (j0 + jj)) * DD + d0 + dd];
        lt[dd][jj] = to_bf16(v);
    }
    __syncthreads();

    int jj2 = t & 63, d4 = t >> 6;
#pragma unroll
    for (int it = 0; it < 16; ++it) {
        int dd2 = d4 * 16 + it;
        featT[((size_t)(b * DD) + (d0 + dd2)) * NN + j0 + jj2] = lt[dd2][jj2];
    }
}

// ---------------- kernel 2: sdep + masked softmax -> bf16 weights ---------
// R6 body verbatim.
__global__ __launch_bounds__(256) void k_score(const float* __restrict__ adj,
                                               const float* __restrict__ snbr,
                                               const float* __restrict__ sasp,
                                               const int* __restrict__ aspect,
                                               const float* __restrict__ watt,
                                               unsigned short* __restrict__ wtsB,
                                               int* __restrict__ upd)
{
    int bi  = blockIdx.x;          // b*N + i
    int b   = bi >> 9;
    int tid = threadIdx.x;
    int g = tid >> 4, l = tid & 15;

    __shared__ float sdep[NN];     // -INF = masked
    __shared__ float sred[4];

    float4 wd = *(const float4*)(watt + DD + l * 4);   // w_dep = w[768:832]

    const float* arow = adj + (size_t)bi * NN * DEPD;
#pragma unroll 4
    for (int it = 0; it < NN / 16; ++it) {
        int j = it * 16 + g;
        float4 a = *(const float4*)(arow + (size_t)j * DEPD + l * 4);
        float p  = a.x*wd.x + a.y*wd.y + a.z*wd.z + a.w*wd.w;
        int   nz = (a.x != 0.f) | (a.y != 0.f) | (a.z != 0.f) | (a.w != 0.f);
        unsigned long long bal = __ballot(nz);
        unsigned int gnz = (unsigned int)((bal >> ((g & 3) * 16)) & 0xFFFFull);
        p += __shfl_xor(p, 1);
        p += __shfl_xor(p, 2);
        p += __shfl_xor(p, 4);
        p += __shfl_xor(p, 8);
        if (l == 0) sdep[j] = gnz ? p : -INFINITY;
    }
    __syncthreads();

    float sa = sasp[bi];
    int j0 = tid, j1 = tid + 256;
    float d0 = sdep[j0], d1 = sdep[j1];
    float sc0 = d0 + snbr[(b << 9) + j0] + sa;   // -INF stays -INF
    float sc1 = d1 + snbr[(b << 9) + j1] + sa;

    float v = fmaxf(sc0, sc1);
#pragma unroll
    for (int off = 1; off < 64; off <<= 1) v = fmaxf(v, __shfl_xor(v, off));
    if ((tid & 63) == 0) sred[tid >> 6] = v;
    __syncthreads();
    float mx = fmaxf(fmaxf(sred[0], sred[1]), fmaxf(sred[2], sred[3]));
    __syncthreads();

    float e0 = d0 > -1e37f ? __expf(sc0 - mx) : 0.f;
    float e1 = d1 > -1e37f ? __expf(sc1 - mx) : 0.f;
    v = e0 + e1;
#pragma unroll
    for (int off = 1; off < 64; off <<= 1) v += __shfl_xor(v, off);
    if ((tid & 63) == 0) sred[tid >> 6] = v;
    __syncthreads();
    float sm = sred[0] + sred[1] + sred[2] + sred[3];

    float inv = sm > 0.f ? 1.f / sm : 0.f;
    size_t wb = (size_t)bi * NN;
    wtsB[wb + j0] = to_bf16(e0 * inv);     // coalesced 2B stores
    wtsB[wb + j1] = to_bf16(e1 * inv);
    if (tid == 0) upd[bi] = (aspect[bi] != 0) && (mx > -1e37f);
}

// ---------------- kernel 3: MFMA agg: out = upd ? W@F : feat --------------
// A = wtsB[b][i][j] (row-major, k-contig), B = featT[b][d][j] (k-contig).
// mfma_f32_16x16x32_bf16; lane l: A row l&15 / B col l&15, k = 8*(l>>4)+e.
// C/D (m89-verified): col = lane&15 (d), row = 4*(lane>>4)+reg (i).
// 4 waves/block in 2x2 -> block tile 32i x 32d. No LDS.
__global__ __launch_bounds__(256) void k_agg(const unsigned short* __restrict__ wtsB,
                                             const unsigned short* __restrict__ featT,
                                             const float* __restrict__ feat,
                                             const int* __restrict__ upd,
                                             float* __restrict__ out)
{
    int b    = blockIdx.z;
    int wave = threadIdx.x >> 6;
    int l    = threadIdx.x & 63;
    int i0   = blockIdx.y * 32 + (wave >> 1) * 16;
    int d0   = blockIdx.x * 32 + (wave & 1) * 16;
    int lr   = l & 15, lg = l >> 4;

    const unsigned short* wrow = wtsB  + ((size_t)(b * NN + i0 + lr)) * NN + lg * 8;
    const unsigned short* frow = featT + ((size_t)(b * DD + d0 + lr)) * NN + lg * 8;

    f32x4 acc = {0.f, 0.f, 0.f, 0.f};
#pragma unroll
    for (int k = 0; k < NN; k += 32) {
        bf16x8 av = *(const bf16x8*)(wrow + k);
        bf16x8 bv = *(const bf16x8*)(frow + k);
        acc = __builtin_amdgcn_mfma_f32_16x16x32_bf16(av, bv, acc, 0, 0, 0);
    }

    int dcol = d0 + lr;
#pragma unroll
    for (int reg = 0; reg < 4; ++reg) {
        int ii   = i0 + lg * 4 + reg;
        int rowi = b * NN + ii;
        float o  = upd[rowi] ? acc[reg] : feat[(size_t)rowi * DD + dcol];
        out[(size_t)rowi * DD + dcol] = o;
    }
}

extern "C" void kernel_launch(void* const* d_in, const int* in_sizes, int n_in,
                              void* d_out, int out_size, void* d_ws, size_t ws_size,
                              hipStream_t stream)
{
    (void)in_sizes; (void)n_in; (void)out_size; (void)ws_size;
    const float* feat = (const float*)d_in[0];
    const int*   asp  = (const int*)d_in[1];
    const float* adj  = (const float*)d_in[2];
    const float* watt = (const float*)d_in[3];
    float* out = (float*)d_out;

    // workspace: wtsB bf16 [8][512][512] (4MB) | featT bf16 [8][768][512]
    // (6.3MB) | snbr | sasp | upd
    unsigned short* wtsB  = (unsigned short*)d_ws;
    unsigned short* featT = wtsB + (size_t)BB * NN * NN;
    float* snbr = (float*)(featT + (size_t)BB * DD * NN);
    float* sasp = snbr + BB * NN;
    int*   upd  = (int*)(sasp + BB * NN);

    k_proj<<<BB * NN / 4, 256, 0, stream>>>(feat, watt, snbr, sasp);
    dim3 gc(DD / 64, NN / 64, BB);
    k_cast<<<gc, 256, 0, stream>>>(feat, featT);
    k_score<<<BB * NN, 256, 0, stream>>>(adj, snbr, sasp, asp, watt, wtsB, upd);
    dim3 ga(DD / 32, NN / 32, BB);
    k_agg<<<ga, 256, 0, stream>>>(wtsB, featT, feat, upd, out);
}